// Round 1
// baseline (133.880 us; speedup 1.0000x reference)
//
#include <hip/hip_runtime.h>
#include <hip/hip_bf16.h>
#include <stdint.h>

#define BATCH 16384
#define INF   1024
#define OUTF  2048

#define BM 128
#define BN 128
#define BK 32

using bf16x8 = __attribute__((ext_vector_type(8))) __bf16;
using f32x4  = __attribute__((ext_vector_type(4))) float;
typedef unsigned short u16;

// round-to-nearest-even f32 -> bf16 (bit pattern)
__device__ __forceinline__ u16 f2bf(float f) {
  unsigned u = __builtin_bit_cast(unsigned, f);
  u += 0x7fffu + ((u >> 16) & 1u);
  return (u16)(u >> 16);
}

__device__ __forceinline__ void load_lds16(const void* g, void* l) {
  __builtin_amdgcn_global_load_lds(
      (const __attribute__((address_space(1))) unsigned*)g,
      (__attribute__((address_space(3))) unsigned*)l, 16, 0, 0);
}

// ---- x: fp32 [BATCH][INF] -> bf16 [BATCH][INF] + row sum-of-squares (fp32) ----
__global__ void __launch_bounds__(256) k_convert_x(const float* __restrict__ x,
                                                   u16* __restrict__ xb,
                                                   float* __restrict__ xsq) {
  const int row = blockIdx.x;
  const int t = threadIdx.x;
  const float4 v = reinterpret_cast<const float4*>(x + (size_t)row * INF)[t];
  ushort4 b4;
  b4.x = f2bf(v.x); b4.y = f2bf(v.y); b4.z = f2bf(v.z); b4.w = f2bf(v.w);
  reinterpret_cast<ushort4*>(xb + (size_t)row * INF)[t] = b4;

  float s = v.x * v.x + v.y * v.y + v.z * v.z + v.w * v.w;
  #pragma unroll
  for (int off = 32; off > 0; off >>= 1) s += __shfl_xor(s, off, 64);
  __shared__ float red[4];
  if ((t & 63) == 0) red[t >> 6] = s;
  __syncthreads();
  if (t == 0) xsq[row] = red[0] + red[1] + red[2] + red[3];
}

// ---- w: fp32 [INF][OUTF] -> bf16 w^T [OUTF][INF] (tiled LDS transpose) ----
__global__ void __launch_bounds__(256) k_convert_w(const float* __restrict__ w,
                                                   u16* __restrict__ wt) {
  __shared__ float tile[64][65];
  const int n0 = blockIdx.x * 64;   // along OUTF
  const int k0 = blockIdx.y * 64;   // along INF
  const int t = threadIdx.x;
  const int c = t & 63, r4 = t >> 6;
  #pragma unroll
  for (int i = 0; i < 16; ++i) {
    int k = r4 + i * 4;
    tile[k][c] = w[(size_t)(k0 + k) * OUTF + n0 + c];   // coalesced over n
  }
  __syncthreads();
  #pragma unroll
  for (int i = 0; i < 16; ++i) {
    int n = r4 + i * 4;
    wt[(size_t)(n0 + n) * INF + k0 + c] = f2bf(tile[c][n]);  // coalesced over k
  }
}

// ---- w_sq: deterministic two-stage column reduction (no atomics) ----
__global__ void __launch_bounds__(256) k_wsq_partial(const float* __restrict__ w,
                                                     float* __restrict__ part) {
  const int col = blockIdx.x * 256 + threadIdx.x;
  const int kb = blockIdx.y;
  float s = 0.f;
  #pragma unroll 4
  for (int k = kb * 64; k < kb * 64 + 64; ++k) {
    float v = w[(size_t)k * OUTF + col];
    s += v * v;
  }
  part[(size_t)kb * OUTF + col] = s;
}

__global__ void __launch_bounds__(256) k_wsq_final(const float* __restrict__ part,
                                                   float* __restrict__ wsq) {
  const int col = blockIdx.x * 256 + threadIdx.x;
  float s = 0.f;
  #pragma unroll
  for (int kb = 0; kb < 16; ++kb) s += part[(size_t)kb * OUTF + col];
  wsq[col] = s;
}

// ---- fused GEMM: out = xsq[row] + wsq[col] - 2 * (x @ w) ----
// A = xb [BATCH][INF] bf16 row-major, B = wt [OUTF][INF] bf16 row-major (B^T layout)
__global__ void __launch_bounds__(256) k_gemm(const u16* __restrict__ A,
                                              const u16* __restrict__ B,
                                              const float* __restrict__ xsq,
                                              const float* __restrict__ wsq,
                                              float* __restrict__ out) {
  __shared__ __attribute__((aligned(16))) u16 As[BM * BK];  // [128][32] linear
  __shared__ __attribute__((aligned(16))) u16 Bs[BN * BK];

  const int t = threadIdx.x;
  const int wave = t >> 6, lane = t & 63;
  const int colBase = blockIdx.x * BN;
  const int rowBase = blockIdx.y * BM;
  const int wr = wave >> 1, wc = wave & 1;  // wave -> 2x2 grid of 64x64 subtiles

  f32x4 acc[4][4] = {};

  // staging: per issue, a wave's 64 lanes cover 16 rows x 32 k (1KB), linear LDS
  const int srow = lane >> 2;        // 0..15
  const int skel = (lane & 3) * 8;   // k-element offset (16B per lane)

  for (int k0 = 0; k0 < INF; k0 += BK) {
    #pragma unroll
    for (int i = 0; i < 2; ++i) {
      const int r = i * 64 + wave * 16 + srow;
      load_lds16(A + (size_t)(rowBase + r) * INF + k0 + skel, &As[r * BK + skel]);
      load_lds16(B + (size_t)(colBase + r) * INF + k0 + skel, &Bs[r * BK + skel]);
    }
    __syncthreads();  // drains vmcnt -> staged data visible

    const int kf = (lane >> 4) * 8;  // k-group per lane
    const int rf = lane & 15;        // row/col within fragment
    bf16x8 a[4], b[4];
    #pragma unroll
    for (int m = 0; m < 4; ++m)
      a[m] = *reinterpret_cast<const bf16x8*>(&As[(wr * 64 + m * 16 + rf) * BK + kf]);
    #pragma unroll
    for (int n = 0; n < 4; ++n)
      b[n] = *reinterpret_cast<const bf16x8*>(&Bs[(wc * 64 + n * 16 + rf) * BK + kf]);

    #pragma unroll
    for (int m = 0; m < 4; ++m)
      #pragma unroll
      for (int n = 0; n < 4; ++n)
        acc[m][n] = __builtin_amdgcn_mfma_f32_16x16x32_bf16(a[m], b[n], acc[m][n], 0, 0, 0);

    __syncthreads();  // protect LDS from next iteration's staging
  }

  // epilogue: C/D layout col = lane&15, row = (lane>>4)*4 + reg
  const int cj = lane & 15;
  const int rg = (lane >> 4) * 4;
  #pragma unroll
  for (int m = 0; m < 4; ++m) {
    #pragma unroll
    for (int j = 0; j < 4; ++j) {
      const int row = rowBase + wr * 64 + m * 16 + rg + j;
      const float xs = xsq[row];
      #pragma unroll
      for (int n = 0; n < 4; ++n) {
        const int col = colBase + wc * 64 + n * 16 + cj;
        out[(size_t)row * OUTF + col] = xs + wsq[col] - 2.0f * acc[m][n][j];
      }
    }
  }
}

extern "C" void kernel_launch(void* const* d_in, const int* in_sizes, int n_in,
                              void* d_out, int out_size, void* d_ws, size_t ws_size,
                              hipStream_t stream) {
  const float* x = (const float*)d_in[0];
  const float* w = (const float*)d_in[1];
  float* out = (float*)d_out;

  char* ws = (char*)d_ws;
  u16* xb    = (u16*)(ws);                    // 16384*1024*2 = 33554432 B
  u16* wt    = (u16*)(ws + 33554432);         // 2048*1024*2  =  4194304 B
  float* xsq = (float*)(ws + 37748736);       // 16384*4      =    65536 B
  float* wsq = (float*)(ws + 37814272);       // 2048*4       =     8192 B
  float* prt = (float*)(ws + 37822464);       // 16*2048*4    =   131072 B

  k_convert_x<<<BATCH, 256, 0, stream>>>(x, xb, xsq);
  k_convert_w<<<dim3(OUTF / 64, INF / 64), 256, 0, stream>>>(w, wt);
  k_wsq_partial<<<dim3(OUTF / 256, 16), 256, 0, stream>>>(w, prt);
  k_wsq_final<<<OUTF / 256, 256, 0, stream>>>(prt, wsq);
  k_gemm<<<dim3(OUTF / BN, BATCH / BM), 256, 0, stream>>>(xb, wt, xsq, wsq, out);
}

// Round 2
// 111.835 us; speedup vs baseline: 1.1971x; 1.1971x over previous
//
#include <hip/hip_runtime.h>
#include <hip/hip_bf16.h>
#include <stdint.h>

#define BATCH 16384
#define INF   1024
#define OUTF  2048

#define BM 256
#define BN 256
#define BK 64
#define NT (INF / BK)   // 16 K-tiles

using bf16x8 = __attribute__((ext_vector_type(8))) __bf16;
using f32x4  = __attribute__((ext_vector_type(4))) float;
typedef unsigned short u16;

// round-to-nearest-even f32 -> bf16 (bit pattern)
__device__ __forceinline__ u16 f2bf(float f) {
  unsigned u = __builtin_bit_cast(unsigned, f);
  u += 0x7fffu + ((u >> 16) & 1u);
  return (u16)(u >> 16);
}

__device__ __forceinline__ void load_lds16(const void* g, void* l) {
  __builtin_amdgcn_global_load_lds(
      (const __attribute__((address_space(1))) unsigned*)g,
      (__attribute__((address_space(3))) unsigned*)l, 16, 0, 0);
}

// ---- x: fp32 [BATCH][INF] -> bf16 [BATCH][INF] + row sum-of-squares (fp32) ----
__global__ void __launch_bounds__(256) k_convert_x(const float* __restrict__ x,
                                                   u16* __restrict__ xb,
                                                   float* __restrict__ xsq) {
  const int row = blockIdx.x;
  const int t = threadIdx.x;
  const float4 v = reinterpret_cast<const float4*>(x + (size_t)row * INF)[t];
  ushort4 b4;
  b4.x = f2bf(v.x); b4.y = f2bf(v.y); b4.z = f2bf(v.z); b4.w = f2bf(v.w);
  reinterpret_cast<ushort4*>(xb + (size_t)row * INF)[t] = b4;

  float s = v.x * v.x + v.y * v.y + v.z * v.z + v.w * v.w;
  #pragma unroll
  for (int off = 32; off > 0; off >>= 1) s += __shfl_xor(s, off, 64);
  __shared__ float red[4];
  if ((t & 63) == 0) red[t >> 6] = s;
  __syncthreads();
  if (t == 0) xsq[row] = red[0] + red[1] + red[2] + red[3];
}

// ---- w: fp32 [INF][OUTF] -> bf16 w^T [OUTF][INF] (tiled LDS transpose) ----
__global__ void __launch_bounds__(256) k_convert_w(const float* __restrict__ w,
                                                   u16* __restrict__ wt) {
  __shared__ float tile[64][65];
  const int n0 = blockIdx.x * 64;   // along OUTF
  const int k0 = blockIdx.y * 64;   // along INF
  const int t = threadIdx.x;
  const int c = t & 63, r4 = t >> 6;
  #pragma unroll
  for (int i = 0; i < 16; ++i) {
    int k = r4 + i * 4;
    tile[k][c] = w[(size_t)(k0 + k) * OUTF + n0 + c];   // coalesced over n
  }
  __syncthreads();
  #pragma unroll
  for (int i = 0; i < 16; ++i) {
    int n = r4 + i * 4;
    wt[(size_t)(n0 + n) * INF + k0 + c] = f2bf(tile[c][n]);  // coalesced over k
  }
}

// ---- w_sq: deterministic two-stage column reduction (no atomics) ----
__global__ void __launch_bounds__(256) k_wsq_partial(const float* __restrict__ w,
                                                     float* __restrict__ part) {
  const int col = blockIdx.x * 256 + threadIdx.x;
  const int kb = blockIdx.y;
  float s = 0.f;
  #pragma unroll 4
  for (int k = kb * 64; k < kb * 64 + 64; ++k) {
    float v = w[(size_t)k * OUTF + col];
    s += v * v;
  }
  part[(size_t)kb * OUTF + col] = s;
}

__global__ void __launch_bounds__(256) k_wsq_final(const float* __restrict__ part,
                                                   float* __restrict__ wsq) {
  const int col = blockIdx.x * 256 + threadIdx.x;
  float s = 0.f;
  #pragma unroll
  for (int kb = 0; kb < 16; ++kb) s += part[(size_t)kb * OUTF + col];
  wsq[col] = s;
}

// ---- fused GEMM: out = xsq[row] + wsq[col] - 2 * (x @ w) ----
// 256x256 tile, BK=64, 8 waves (2Mx4N), double-buffered 128 KiB LDS,
// counted-vmcnt pipeline (2 K-tiles in flight), T2 XOR-swizzle, T5 setprio.
// LDS layout per buffer (65536 B): A [256][64] bf16 at +0, B [256][64] at +32768.
// Swizzle: element (r, c-byte) lives at LDS byte r*128 + (c ^ ((r&7)<<4)).
__global__ void __launch_bounds__(512, 2) k_gemm(const u16* __restrict__ A,
                                                 const u16* __restrict__ Bt,
                                                 const float* __restrict__ xsq,
                                                 const float* __restrict__ wsq,
                                                 float* __restrict__ out) {
  extern __shared__ __attribute__((aligned(16))) char lds_raw[];

  const int tid = threadIdx.x;
  const int wave = tid >> 6, lane = tid & 63;
  // T1: XCD-pinned column strips. grid=512, bid%8 -> XCD -> N-strip.
  const int bx = blockIdx.x & 7;        // N block (8 strips)
  const int by = blockIdx.x >> 3;       // M block (64)
  const int rowBase = by * BM;
  const int colBase = bx * BN;
  const int wr = wave >> 2, wc = wave & 3;   // 2 (M) x 4 (N) waves

  // ---- staging addresses (both-sides swizzle: linear LDS dest, pre-swizzled src) ----
  // LDS dest byte (within operand tile) = i*8192 + tid*16  ->  row = i*64 + tid/8,
  // col-byte c' = (tid&7)*16. Source col-byte = c' ^ ((row&7)<<4); row&7 = (tid>>3)&7.
  const int srow  = tid >> 3;
  const int ke    = (((tid & 7) * 16) ^ (((tid >> 3) & 7) << 4)) >> 1; // element col, const/thread
  const u16* aS = A  + (size_t)(rowBase + srow) * INF + ke;
  const u16* bS = Bt + (size_t)(colBase + srow) * INF + ke;
  char* ldsw = lds_raw + tid * 16;

  auto STAGE = [&](int parity, int t) {
    const int kk = t * BK;
    char* dst = ldsw + parity * 65536;
    #pragma unroll
    for (int i = 0; i < 4; ++i)
      load_lds16(aS + (size_t)(i * 64) * INF + kk, dst + i * 8192);
    #pragma unroll
    for (int i = 0; i < 4; ++i)
      load_lds16(bS + (size_t)(i * 64) * INF + kk, dst + 32768 + i * 8192);
  };

  // ---- fragment read addressing (swizzled) ----
  const int rf  = lane & 15;
  const int hi  = lane >> 4;                 // 0..3 (k-group)
  const int swz = (rf & 7) << 4;
  const int aRd = (wr * 128 + rf) * 128;            // + m*2048 + ((ks*64+hi*16)^swz)
  const int bRd = 32768 + (wc * 64 + rf) * 128;     // + n*2048 + ((ks*64+hi*16)^swz)

  f32x4 acc[8][4] = {};

  // prologue: 2 K-tiles in flight
  STAGE(0, 0);
  STAGE(1, 1);

  #pragma unroll
  for (int t = 0; t < NT; ++t) {
    if (t < NT - 1) { asm volatile("s_waitcnt vmcnt(8)" ::: "memory"); }
    else            { asm volatile("s_waitcnt vmcnt(0)" ::: "memory"); }
    __builtin_amdgcn_s_barrier();            // buf[t&1] resident for all waves

    const char* buf = lds_raw + (t & 1) * 65536;

    #pragma unroll
    for (int q = 0; q < 4; ++q) {            // quadrant phases
      const int mh = q >> 1, nh = q & 1;
      bf16x8 a[4][2], b[2][2];
      #pragma unroll
      for (int mm = 0; mm < 4; ++mm)
        #pragma unroll
        for (int ks = 0; ks < 2; ++ks)
          a[mm][ks] = *reinterpret_cast<const bf16x8*>(
              buf + aRd + (mh * 4 + mm) * 2048 + ((ks * 64 + hi * 16) ^ swz));
      #pragma unroll
      for (int nn = 0; nn < 2; ++nn)
        #pragma unroll
        for (int ks = 0; ks < 2; ++ks)
          b[nn][ks] = *reinterpret_cast<const bf16x8*>(
              buf + bRd + (nh * 2 + nn) * 2048 + ((ks * 64 + hi * 16) ^ swz));

      __builtin_amdgcn_s_setprio(1);
      #pragma unroll
      for (int mm = 0; mm < 4; ++mm)
        #pragma unroll
        for (int nn = 0; nn < 2; ++nn)
          #pragma unroll
          for (int ks = 0; ks < 2; ++ks)
            acc[mh * 4 + mm][nh * 2 + nn] = __builtin_amdgcn_mfma_f32_16x16x32_bf16(
                a[mm][ks], b[nn][ks], acc[mh * 4 + mm][nh * 2 + nn], 0, 0, 0);
      __builtin_amdgcn_s_setprio(0);
    }

    asm volatile("s_waitcnt lgkmcnt(0)" ::: "memory");  // my reads of buf[t&1] landed
    __builtin_amdgcn_s_barrier();                        // everyone done reading
    if (t + 2 < NT) STAGE(t & 1, t + 2);                 // overwrite freed buffer
  }

  // ---- epilogue: C/D layout col = lane&15, row = (lane>>4)*4 + j ----
  const int cj = lane & 15;
  const int rg = hi * 4;
  #pragma unroll
  for (int m = 0; m < 8; ++m) {
    #pragma unroll
    for (int j = 0; j < 4; ++j) {
      const int row = rowBase + wr * 128 + m * 16 + rg + j;
      const float xs = xsq[row];
      #pragma unroll
      for (int n = 0; n < 4; ++n) {
        const int col = colBase + wc * 64 + n * 16 + cj;
        out[(size_t)row * OUTF + col] = xs + wsq[col] - 2.0f * acc[m][n][j];
      }
    }
  }
}

extern "C" void kernel_launch(void* const* d_in, const int* in_sizes, int n_in,
                              void* d_out, int out_size, void* d_ws, size_t ws_size,
                              hipStream_t stream) {
  const float* x = (const float*)d_in[0];
  const float* w = (const float*)d_in[1];
  float* out = (float*)d_out;

  char* ws = (char*)d_ws;
  u16* xb    = (u16*)(ws);                    // 16384*1024*2 = 33554432 B
  u16* wt    = (u16*)(ws + 33554432);         // 2048*1024*2  =  4194304 B
  float* xsq = (float*)(ws + 37748736);       // 16384*4      =    65536 B
  float* wsq = (float*)(ws + 37814272);       // 2048*4       =     8192 B
  float* prt = (float*)(ws + 37822464);       // 16*2048*4    =   131072 B

  (void)hipFuncSetAttribute(reinterpret_cast<const void*>(k_gemm),
                            hipFuncAttributeMaxDynamicSharedMemorySize, 131072);

  k_convert_x<<<BATCH, 256, 0, stream>>>(x, xb, xsq);
  k_convert_w<<<dim3(OUTF / 64, INF / 64), 256, 0, stream>>>(w, wt);
  k_wsq_partial<<<dim3(OUTF / 256, 16), 256, 0, stream>>>(w, prt);
  k_wsq_final<<<OUTF / 256, 256, 0, stream>>>(prt, wsq);
  k_gemm<<<512, 512, 131072, stream>>>(xb, wt, xsq, wsq, out);
}

// Round 3
// 108.912 us; speedup vs baseline: 1.2293x; 1.0268x over previous
//
#include <hip/hip_runtime.h>
#include <hip/hip_bf16.h>
#include <stdint.h>

#define BATCH 16384
#define INF   1024
#define OUTF  2048

#define BM 256
#define BN 256
#define BK 64
#define NT (INF / BK)   // 16 K-tiles

using bf16x8 = __attribute__((ext_vector_type(8))) __bf16;
using f32x4  = __attribute__((ext_vector_type(4))) float;
typedef unsigned short u16;

// round-to-nearest-even f32 -> bf16 (bit pattern)
__device__ __forceinline__ u16 f2bf(float f) {
  unsigned u = __builtin_bit_cast(unsigned, f);
  u += 0x7fffu + ((u >> 16) & 1u);
  return (u16)(u >> 16);
}

__device__ __forceinline__ void load_lds16(const void* g, void* l) {
  __builtin_amdgcn_global_load_lds(
      (const __attribute__((address_space(1))) unsigned*)g,
      (__attribute__((address_space(3))) unsigned*)l, 16, 0, 0);
}

// ---- x: fp32 [BATCH][INF] -> bf16 [BATCH][INF] + row sum-of-squares (fp32) ----
__global__ void __launch_bounds__(256) k_convert_x(const float* __restrict__ x,
                                                   u16* __restrict__ xb,
                                                   float* __restrict__ xsq) {
  const int row = blockIdx.x;
  const int t = threadIdx.x;
  const float4 v = reinterpret_cast<const float4*>(x + (size_t)row * INF)[t];
  ushort4 b4;
  b4.x = f2bf(v.x); b4.y = f2bf(v.y); b4.z = f2bf(v.z); b4.w = f2bf(v.w);
  reinterpret_cast<ushort4*>(xb + (size_t)row * INF)[t] = b4;

  float s = v.x * v.x + v.y * v.y + v.z * v.z + v.w * v.w;
  #pragma unroll
  for (int off = 32; off > 0; off >>= 1) s += __shfl_xor(s, off, 64);
  __shared__ float red[4];
  if ((t & 63) == 0) red[t >> 6] = s;
  __syncthreads();
  if (t == 0) xsq[row] = red[0] + red[1] + red[2] + red[3];
}

// ---- w: fp32 [INF][OUTF] -> bf16 w^T [OUTF][INF] (tiled LDS transpose) ----
__global__ void __launch_bounds__(256) k_convert_w(const float* __restrict__ w,
                                                   u16* __restrict__ wt) {
  __shared__ float tile[64][65];
  const int n0 = blockIdx.x * 64;   // along OUTF
  const int k0 = blockIdx.y * 64;   // along INF
  const int t = threadIdx.x;
  const int c = t & 63, r4 = t >> 6;
  #pragma unroll
  for (int i = 0; i < 16; ++i) {
    int k = r4 + i * 4;
    tile[k][c] = w[(size_t)(k0 + k) * OUTF + n0 + c];   // coalesced over n
  }
  __syncthreads();
  #pragma unroll
  for (int i = 0; i < 16; ++i) {
    int n = r4 + i * 4;
    wt[(size_t)(n0 + n) * INF + k0 + c] = f2bf(tile[c][n]);  // coalesced over k
  }
}

// ---- w_sq: deterministic two-stage column reduction (no atomics) ----
__global__ void __launch_bounds__(256) k_wsq_partial(const float* __restrict__ w,
                                                     float* __restrict__ part) {
  const int col = blockIdx.x * 256 + threadIdx.x;
  const int kb = blockIdx.y;
  float s = 0.f;
  #pragma unroll 4
  for (int k = kb * 64; k < kb * 64 + 64; ++k) {
    float v = w[(size_t)k * OUTF + col];
    s += v * v;
  }
  part[(size_t)kb * OUTF + col] = s;
}

__global__ void __launch_bounds__(256) k_wsq_final(const float* __restrict__ part,
                                                   float* __restrict__ wsq) {
  const int col = blockIdx.x * 256 + threadIdx.x;
  float s = 0.f;
  #pragma unroll
  for (int kb = 0; kb < 16; ++kb) s += part[(size_t)kb * OUTF + col];
  wsq[col] = s;
}

// ---- fused GEMM: out = xsq[row] + wsq[col] - 2 * (x @ w) ----
// 256x256 tile, BK=64, 8 waves (2Mx4N), double-buffered 128 KiB LDS,
// counted-vmcnt pipeline (2 K-tiles in flight), T2 XOR-swizzle, T5 setprio.
// Each fragment is read from LDS exactly ONCE per K-tile (24 ds_read_b128/wave):
// all 8 B-frags held in registers, A-frags loaded per m-half.
// LDS layout per buffer (65536 B): A [256][64] bf16 at +0, B [256][64] at +32768.
// Swizzle: element (r, c-byte) lives at LDS byte r*128 + (c ^ ((r&7)<<4)).
__global__ void __launch_bounds__(512, 2) k_gemm(const u16* __restrict__ A,
                                                 const u16* __restrict__ Bt,
                                                 const float* __restrict__ xsq,
                                                 const float* __restrict__ wsq,
                                                 float* __restrict__ out) {
  extern __shared__ __attribute__((aligned(16))) char lds_raw[];

  const int tid = threadIdx.x;
  const int wave = tid >> 6, lane = tid & 63;
  // T1: XCD-pinned column strips. grid=512, bid%8 -> XCD -> N-strip.
  const int bx = blockIdx.x & 7;        // N block (8 strips)
  const int by = blockIdx.x >> 3;       // M block (64)
  const int rowBase = by * BM;
  const int colBase = bx * BN;
  const int wr = wave >> 2, wc = wave & 3;   // 2 (M) x 4 (N) waves

  // ---- staging addresses (both-sides swizzle: linear LDS dest, pre-swizzled src) ----
  const int srow  = tid >> 3;
  const int ke    = (((tid & 7) * 16) ^ (((tid >> 3) & 7) << 4)) >> 1; // element col, const/thread
  const u16* aS = A  + (size_t)(rowBase + srow) * INF + ke;
  const u16* bS = Bt + (size_t)(colBase + srow) * INF + ke;
  char* ldsw = lds_raw + tid * 16;

  auto STAGE = [&](int parity, int t) {
    const int kk = t * BK;
    char* dst = ldsw + parity * 65536;
    #pragma unroll
    for (int i = 0; i < 4; ++i)
      load_lds16(aS + (size_t)(i * 64) * INF + kk, dst + i * 8192);
    #pragma unroll
    for (int i = 0; i < 4; ++i)
      load_lds16(bS + (size_t)(i * 64) * INF + kk, dst + 32768 + i * 8192);
  };

  // ---- fragment read addressing (swizzled) ----
  const int rf  = lane & 15;
  const int hi  = lane >> 4;                 // 0..3 (k-group)
  const int swz = (rf & 7) << 4;
  const int aRd = (wr * 128 + rf) * 128;            // + m*2048 + ((ks*64+hi*16)^swz)
  const int bRd = 32768 + (wc * 64 + rf) * 128;     // + n*2048 + ((ks*64+hi*16)^swz)

  f32x4 acc[8][4] = {};

  // prologue: 2 K-tiles in flight
  STAGE(0, 0);
  STAGE(1, 1);

  #pragma unroll
  for (int t = 0; t < NT; ++t) {
    if (t < NT - 1) { asm volatile("s_waitcnt vmcnt(8)" ::: "memory"); }
    else            { asm volatile("s_waitcnt vmcnt(0)" ::: "memory"); }
    __builtin_amdgcn_s_barrier();            // buf[t&1] resident for all waves

    const char* buf = lds_raw + (t & 1) * 65536;

    // all B fragments once (8 reads, reused by both m-halves)
    bf16x8 bq[4][2];
    #pragma unroll
    for (int nn = 0; nn < 4; ++nn)
      #pragma unroll
      for (int ks = 0; ks < 2; ++ks)
        bq[nn][ks] = *reinterpret_cast<const bf16x8*>(
            buf + bRd + nn * 2048 + ((ks * 64 + hi * 16) ^ swz));

    #pragma unroll
    for (int mh = 0; mh < 2; ++mh) {
      bf16x8 aq[4][2];
      #pragma unroll
      for (int mm = 0; mm < 4; ++mm)
        #pragma unroll
        for (int ks = 0; ks < 2; ++ks)
          aq[mm][ks] = *reinterpret_cast<const bf16x8*>(
              buf + aRd + (mh * 4 + mm) * 2048 + ((ks * 64 + hi * 16) ^ swz));

      __builtin_amdgcn_s_setprio(1);
      #pragma unroll
      for (int mm = 0; mm < 4; ++mm)
        #pragma unroll
        for (int nn = 0; nn < 4; ++nn)
          #pragma unroll
          for (int ks = 0; ks < 2; ++ks)
            acc[mh * 4 + mm][nn] = __builtin_amdgcn_mfma_f32_16x16x32_bf16(
                aq[mm][ks], bq[nn][ks], acc[mh * 4 + mm][nn], 0, 0, 0);
      __builtin_amdgcn_s_setprio(0);
    }

    asm volatile("s_waitcnt lgkmcnt(0)" ::: "memory");  // my reads of buf[t&1] landed
    __builtin_amdgcn_s_barrier();                        // everyone done reading
    if (t + 2 < NT) STAGE(t & 1, t + 2);                 // overwrite freed buffer
  }

  // ---- epilogue: C/D layout col = lane&15, row = (lane>>4)*4 + j ----
  const int cj = lane & 15;
  const int rg = hi * 4;
  #pragma unroll
  for (int m = 0; m < 8; ++m) {
    #pragma unroll
    for (int j = 0; j < 4; ++j) {
      const int row = rowBase + wr * 128 + m * 16 + rg + j;
      const float xs = xsq[row];
      #pragma unroll
      for (int n = 0; n < 4; ++n) {
        const int col = colBase + wc * 64 + n * 16 + cj;
        out[(size_t)row * OUTF + col] = xs + wsq[col] - 2.0f * acc[m][n][j];
      }
    }
  }
}

extern "C" void kernel_launch(void* const* d_in, const int* in_sizes, int n_in,
                              void* d_out, int out_size, void* d_ws, size_t ws_size,
                              hipStream_t stream) {
  const float* x = (const float*)d_in[0];
  const float* w = (const float*)d_in[1];
  float* out = (float*)d_out;

  char* ws = (char*)d_ws;
  u16* xb    = (u16*)(ws);                    // 16384*1024*2 = 33554432 B
  u16* wt    = (u16*)(ws + 33554432);         // 2048*1024*2  =  4194304 B
  float* xsq = (float*)(ws + 37748736);       // 16384*4      =    65536 B
  float* wsq = (float*)(ws + 37814272);       // 2048*4       =     8192 B
  float* prt = (float*)(ws + 37822464);       // 16*2048*4    =   131072 B

  (void)hipFuncSetAttribute(reinterpret_cast<const void*>(k_gemm),
                            hipFuncAttributeMaxDynamicSharedMemorySize, 131072);

  k_convert_x<<<BATCH, 256, 0, stream>>>(x, xb, xsq);
  k_convert_w<<<dim3(OUTF / 64, INF / 64), 256, 0, stream>>>(w, wt);
  k_wsq_partial<<<dim3(OUTF / 256, 16), 256, 0, stream>>>(w, prt);
  k_wsq_final<<<OUTF / 256, 256, 0, stream>>>(prt, wsq);
  k_gemm<<<512, 512, 131072, stream>>>(xb, wt, xsq, wsq, out);
}

// Round 4
// 99.627 us; speedup vs baseline: 1.3438x; 1.0932x over previous
//
#include <hip/hip_runtime.h>
#include <hip/hip_bf16.h>
#include <stdint.h>

#define BATCH 16384
#define INF   1024
#define OUTF  2048

#define BM 256
#define BN 256
#define BK 64
#define NT (INF / BK)   // 16 K-tiles

using bf16x8 = __attribute__((ext_vector_type(8))) __bf16;
using f32x4  = __attribute__((ext_vector_type(4))) float;
typedef unsigned short u16;

// round-to-nearest-even f32 -> bf16 (bit pattern)
__device__ __forceinline__ u16 f2bf(float f) {
  unsigned u = __builtin_bit_cast(unsigned, f);
  u += 0x7fffu + ((u >> 16) & 1u);
  return (u16)(u >> 16);
}

__device__ __forceinline__ void load_lds16(const void* g, void* l) {
  __builtin_amdgcn_global_load_lds(
      (const __attribute__((address_space(1))) unsigned*)g,
      (__attribute__((address_space(3))) unsigned*)l, 16, 0, 0);
}

// ---- x: fp32 [BATCH][INF] -> bf16 [BATCH][INF] + row sum-of-squares (fp32) ----
__global__ void __launch_bounds__(256) k_convert_x(const float* __restrict__ x,
                                                   u16* __restrict__ xb,
                                                   float* __restrict__ xsq) {
  const int row = blockIdx.x;
  const int t = threadIdx.x;
  const float4 v = reinterpret_cast<const float4*>(x + (size_t)row * INF)[t];
  ushort4 b4;
  b4.x = f2bf(v.x); b4.y = f2bf(v.y); b4.z = f2bf(v.z); b4.w = f2bf(v.w);
  reinterpret_cast<ushort4*>(xb + (size_t)row * INF)[t] = b4;

  float s = v.x * v.x + v.y * v.y + v.z * v.z + v.w * v.w;
  #pragma unroll
  for (int off = 32; off > 0; off >>= 1) s += __shfl_xor(s, off, 64);
  __shared__ float red[4];
  if ((t & 63) == 0) red[t >> 6] = s;
  __syncthreads();
  if (t == 0) xsq[row] = red[0] + red[1] + red[2] + red[3];
}

// ---- w: fp32 [INF][OUTF] -> bf16 w^T [OUTF][INF] + fused per-column sq-partials ----
__global__ void __launch_bounds__(256) k_convert_w(const float* __restrict__ w,
                                                   u16* __restrict__ wt,
                                                   float* __restrict__ part) {
  __shared__ float tile[64][65];
  __shared__ float psum[4][64];
  const int n0 = blockIdx.x * 64;   // along OUTF
  const int k0 = blockIdx.y * 64;   // along INF
  const int t = threadIdx.x;
  const int c = t & 63, r4 = t >> 6;
  float s = 0.f;
  #pragma unroll
  for (int i = 0; i < 16; ++i) {
    int k = r4 + i * 4;
    float v = w[(size_t)(k0 + k) * OUTF + n0 + c];   // coalesced over n
    tile[k][c] = v;
    s += v * v;
  }
  psum[r4][c] = s;
  __syncthreads();
  #pragma unroll
  for (int i = 0; i < 16; ++i) {
    int n = r4 + i * 4;
    wt[(size_t)(n0 + n) * INF + k0 + c] = f2bf(tile[c][n]);  // coalesced over k
  }
  if (r4 == 0)
    part[(size_t)blockIdx.y * OUTF + n0 + c] =
        psum[0][c] + psum[1][c] + psum[2][c] + psum[3][c];
}

__global__ void __launch_bounds__(256) k_wsq_final(const float* __restrict__ part,
                                                   float* __restrict__ wsq) {
  const int col = blockIdx.x * 256 + threadIdx.x;
  float s = 0.f;
  #pragma unroll
  for (int kb = 0; kb < 16; ++kb) s += part[(size_t)kb * OUTF + col];
  wsq[col] = s;
}

// ---- fused GEMM: out = xsq[row] + wsq[col] - 2 * (x @ w) ----
// 256x256 tile, BK=64, 8 waves (2Mx4N), double-buffered 128 KiB LDS.
// 4 phases per K-tile: {vmcnt(ph0) -> barrier -> stage 2 -> ds_read group -> 16 MFMA}.
// Staging: B(t+1) at ph0/ph1 (other parity), A(t+2) at ph2/ph3 (same parity,
// into chunks fully consumed >=1 barrier earlier). One vmcnt(4)/K-tile.
// Swizzle (T2): element (r, c-byte) at LDS byte r*128 + (c ^ ((r&7)<<4)),
// applied both-sides (pre-swizzled global source, swizzled ds_read).
__global__ void __launch_bounds__(512, 2) k_gemm(const u16* __restrict__ A,
                                                 const u16* __restrict__ Bt,
                                                 const float* __restrict__ xsq,
                                                 const float* __restrict__ wsq,
                                                 float* __restrict__ out) {
  extern __shared__ __attribute__((aligned(16))) char lds_raw[];

  const int tid = threadIdx.x;
  const int wave = tid >> 6, lane = tid & 63;
  // T1: XCD-pinned column strips. grid=512, bid%8 -> XCD -> N-strip.
  const int bx = blockIdx.x & 7;
  const int by = blockIdx.x >> 3;
  const int rowBase = by * BM;
  const int colBase = bx * BN;
  const int wr = wave >> 2, wc = wave & 3;   // 2 (M) x 4 (N) waves

  // staging addresses (linear LDS dest, pre-swizzled global source)
  const int srow  = tid >> 3;
  const int ke    = (((tid & 7) * 16) ^ (((tid >> 3) & 7) << 4)) >> 1;
  const u16* aS = A  + (size_t)(rowBase + srow) * INF + ke;
  const u16* bS = Bt + (size_t)(colBase + srow) * INF + ke;
  char* ldsw = lds_raw + tid * 16;

  // A chunk i = rows 64i..64i+63 at region i*8192. Group g stages chunks {g, g+2}
  // (g=0: consumed at ph0 by both wr; g=1: consumed at ph2).
  auto STAGE_A = [&](int parity, int t, int g) {
    const int kk = t * BK;
    char* dst = ldsw + parity * 65536;
    load_lds16(aS + (size_t)(g * 64) * INF + kk, dst + g * 8192);
    load_lds16(aS + (size_t)((g + 2) * 64) * INF + kk, dst + (g + 2) * 8192);
  };
  // B group g stages chunks {2g, 2g+1}.
  auto STAGE_B = [&](int parity, int t, int g) {
    const int kk = t * BK;
    char* dst = ldsw + parity * 65536 + 32768;
    load_lds16(bS + (size_t)(g * 128) * INF + kk, dst + g * 16384);
    load_lds16(bS + (size_t)(g * 128 + 64) * INF + kk, dst + g * 16384 + 8192);
  };

  // fragment read addressing (swizzled)
  const int rf  = lane & 15;
  const int hi  = lane >> 4;
  const int swz = (rf & 7) << 4;
  const int aRd = (wr * 128 + rf) * 128;
  const int bRd = 32768 + (wc * 64 + rf) * 128;

  f32x4 acc[8][4] = {};

  // prologue: tiles 0 fully + tile 1 A-groups (12 loads -> steady state)
  STAGE_A(0, 0, 0); STAGE_A(0, 0, 1);
  STAGE_B(0, 0, 0); STAGE_B(0, 0, 1);
  STAGE_A(1, 1, 0); STAGE_A(1, 1, 1);

  #pragma unroll
  for (int t = 0; t < NT; ++t) {
    const char* buf = lds_raw + (t & 1) * 65536;
    const int op = (t & 1) ^ 1;

    bf16x8 a0[4][2], a1[4][2], b0[2][2], b1[2][2];

    // ---------- phase 0: quadrant (0,0) ----------
    if (t < NT - 1) asm volatile("s_waitcnt vmcnt(4)" ::: "memory");
    else            asm volatile("s_waitcnt vmcnt(0)" ::: "memory");
    __builtin_amdgcn_s_barrier();
    if (t + 1 < NT) STAGE_B(op, t + 1, 0);
    #pragma unroll
    for (int mm = 0; mm < 4; ++mm)
      #pragma unroll
      for (int ks = 0; ks < 2; ++ks)
        a0[mm][ks] = *reinterpret_cast<const bf16x8*>(
            buf + aRd + mm * 2048 + ((ks * 64 + hi * 16) ^ swz));
    #pragma unroll
    for (int nn = 0; nn < 2; ++nn)
      #pragma unroll
      for (int ks = 0; ks < 2; ++ks)
        b0[nn][ks] = *reinterpret_cast<const bf16x8*>(
            buf + bRd + nn * 2048 + ((ks * 64 + hi * 16) ^ swz));
    __builtin_amdgcn_s_setprio(1);
    #pragma unroll
    for (int mm = 0; mm < 4; ++mm)
      #pragma unroll
      for (int nn = 0; nn < 2; ++nn)
        #pragma unroll
        for (int ks = 0; ks < 2; ++ks)
          acc[mm][nn] = __builtin_amdgcn_mfma_f32_16x16x32_bf16(
              a0[mm][ks], b0[nn][ks], acc[mm][nn], 0, 0, 0);
    __builtin_amdgcn_s_setprio(0);

    // ---------- phase 1: quadrant (0,1) ----------
    __builtin_amdgcn_s_barrier();
    if (t + 1 < NT) STAGE_B(op, t + 1, 1);
    #pragma unroll
    for (int nn = 0; nn < 2; ++nn)
      #pragma unroll
      for (int ks = 0; ks < 2; ++ks)
        b1[nn][ks] = *reinterpret_cast<const bf16x8*>(
            buf + bRd + (2 + nn) * 2048 + ((ks * 64 + hi * 16) ^ swz));
    __builtin_amdgcn_s_setprio(1);
    #pragma unroll
    for (int mm = 0; mm < 4; ++mm)
      #pragma unroll
      for (int nn = 0; nn < 2; ++nn)
        #pragma unroll
        for (int ks = 0; ks < 2; ++ks)
          acc[mm][2 + nn] = __builtin_amdgcn_mfma_f32_16x16x32_bf16(
              a0[mm][ks], b1[nn][ks], acc[mm][2 + nn], 0, 0, 0);
    __builtin_amdgcn_s_setprio(0);

    // ---------- phase 2: quadrant (1,1) ----------
    __builtin_amdgcn_sched_barrier(0);
    __builtin_amdgcn_s_barrier();
    if (t + 2 < NT) STAGE_A(t & 1, t + 2, 0);   // chunks {0,2}: consumed at ph0
    #pragma unroll
    for (int mm = 0; mm < 4; ++mm)
      #pragma unroll
      for (int ks = 0; ks < 2; ++ks)
        a1[mm][ks] = *reinterpret_cast<const bf16x8*>(
            buf + aRd + (4 + mm) * 2048 + ((ks * 64 + hi * 16) ^ swz));
    __builtin_amdgcn_s_setprio(1);
    #pragma unroll
    for (int mm = 0; mm < 4; ++mm)
      #pragma unroll
      for (int nn = 0; nn < 2; ++nn)
        #pragma unroll
        for (int ks = 0; ks < 2; ++ks)
          acc[4 + mm][2 + nn] = __builtin_amdgcn_mfma_f32_16x16x32_bf16(
              a1[mm][ks], b1[nn][ks], acc[4 + mm][2 + nn], 0, 0, 0);
    __builtin_amdgcn_s_setprio(0);

    // ---------- phase 3: quadrant (1,0) ----------
    __builtin_amdgcn_sched_barrier(0);
    __builtin_amdgcn_s_barrier();
    if (t + 2 < NT) STAGE_A(t & 1, t + 2, 1);   // chunks {1,3}: consumed at ph2
    __builtin_amdgcn_s_setprio(1);
    #pragma unroll
    for (int mm = 0; mm < 4; ++mm)
      #pragma unroll
      for (int nn = 0; nn < 2; ++nn)
        #pragma unroll
        for (int ks = 0; ks < 2; ++ks)
          acc[4 + mm][nn] = __builtin_amdgcn_mfma_f32_16x16x32_bf16(
              a1[mm][ks], b0[nn][ks], acc[4 + mm][nn], 0, 0, 0);
    __builtin_amdgcn_s_setprio(0);
  }

  // ---- epilogue: C/D layout col = lane&15, row = (lane>>4)*4 + j ----
  const int cj = lane & 15;
  const int rg = hi * 4;
  #pragma unroll
  for (int m = 0; m < 8; ++m) {
    #pragma unroll
    for (int j = 0; j < 4; ++j) {
      const int row = rowBase + wr * 128 + m * 16 + rg + j;
      const float xs = xsq[row];
      #pragma unroll
      for (int n = 0; n < 4; ++n) {
        const int col = colBase + wc * 64 + n * 16 + cj;
        out[(size_t)row * OUTF + col] = xs + wsq[col] - 2.0f * acc[m][n][j];
      }
    }
  }
}

extern "C" void kernel_launch(void* const* d_in, const int* in_sizes, int n_in,
                              void* d_out, int out_size, void* d_ws, size_t ws_size,
                              hipStream_t stream) {
  const float* x = (const float*)d_in[0];
  const float* w = (const float*)d_in[1];
  float* out = (float*)d_out;

  char* ws = (char*)d_ws;
  u16* xb    = (u16*)(ws);                    // 16384*1024*2 = 33554432 B
  u16* wt    = (u16*)(ws + 33554432);         // 2048*1024*2  =  4194304 B
  float* xsq = (float*)(ws + 37748736);       // 16384*4      =    65536 B
  float* wsq = (float*)(ws + 37814272);       // 2048*4       =     8192 B
  float* prt = (float*)(ws + 37822464);       // 16*2048*4    =   131072 B

  (void)hipFuncSetAttribute(reinterpret_cast<const void*>(k_gemm),
                            hipFuncAttributeMaxDynamicSharedMemorySize, 131072);

  k_convert_x<<<BATCH, 256, 0, stream>>>(x, xb, xsq);
  k_convert_w<<<dim3(OUTF / 64, INF / 64), 256, 0, stream>>>(w, wt, prt);
  k_wsq_final<<<OUTF / 256, 256, 0, stream>>>(prt, wsq);
  k_gemm<<<512, 512, 131072, stream>>>(xb, wt, xsq, wsq, out);
}

// Round 5
// 99.319 us; speedup vs baseline: 1.3480x; 1.0031x over previous
//
#include <hip/hip_runtime.h>
#include <hip/hip_bf16.h>
#include <stdint.h>

#define BATCH 16384
#define INF   1024
#define OUTF  2048

#define BM 256
#define BN 256
#define BK 64
#define NT (INF / BK)   // 16 K-tiles

using bf16x8 = __attribute__((ext_vector_type(8))) __bf16;
using f32x4  = __attribute__((ext_vector_type(4))) float;
typedef unsigned short u16;

// round-to-nearest-even f32 -> bf16 (bit pattern)
__device__ __forceinline__ u16 f2bf(float f) {
  unsigned u = __builtin_bit_cast(unsigned, f);
  u += 0x7fffu + ((u >> 16) & 1u);
  return (u16)(u >> 16);
}

__device__ __forceinline__ void load_lds16(const void* g, void* l) {
  __builtin_amdgcn_global_load_lds(
      (const __attribute__((address_space(1))) unsigned*)g,
      (__attribute__((address_space(3))) unsigned*)l, 16, 0, 0);
}

// ---- x: fp32 [BATCH][INF] -> bf16 [BATCH][INF] + row sum-of-squares (fp32) ----
__global__ void __launch_bounds__(256) k_convert_x(const float* __restrict__ x,
                                                   u16* __restrict__ xb,
                                                   float* __restrict__ xsq) {
  const int row = blockIdx.x;
  const int t = threadIdx.x;
  const float4 v = reinterpret_cast<const float4*>(x + (size_t)row * INF)[t];
  ushort4 b4;
  b4.x = f2bf(v.x); b4.y = f2bf(v.y); b4.z = f2bf(v.z); b4.w = f2bf(v.w);
  reinterpret_cast<ushort4*>(xb + (size_t)row * INF)[t] = b4;

  float s = v.x * v.x + v.y * v.y + v.z * v.z + v.w * v.w;
  #pragma unroll
  for (int off = 32; off > 0; off >>= 1) s += __shfl_xor(s, off, 64);
  __shared__ float red[4];
  if ((t & 63) == 0) red[t >> 6] = s;
  __syncthreads();
  if (t == 0) xsq[row] = red[0] + red[1] + red[2] + red[3];
}

// ---- w: fp32 [INF][OUTF] -> bf16 w^T [OUTF][INF] + fused per-column sq-partials ----
__global__ void __launch_bounds__(256) k_convert_w(const float* __restrict__ w,
                                                   u16* __restrict__ wt,
                                                   float* __restrict__ part) {
  __shared__ float tile[64][65];
  __shared__ float psum[4][64];
  const int n0 = blockIdx.x * 64;   // along OUTF
  const int k0 = blockIdx.y * 64;   // along INF
  const int t = threadIdx.x;
  const int c = t & 63, r4 = t >> 6;
  float s = 0.f;
  #pragma unroll
  for (int i = 0; i < 16; ++i) {
    int k = r4 + i * 4;
    float v = w[(size_t)(k0 + k) * OUTF + n0 + c];   // coalesced over n
    tile[k][c] = v;
    s += v * v;
  }
  psum[r4][c] = s;
  __syncthreads();
  #pragma unroll
  for (int i = 0; i < 16; ++i) {
    int n = r4 + i * 4;
    wt[(size_t)(n0 + n) * INF + k0 + c] = f2bf(tile[c][n]);  // coalesced over k
  }
  if (r4 == 0)
    part[(size_t)blockIdx.y * OUTF + n0 + c] =
        psum[0][c] + psum[1][c] + psum[2][c] + psum[3][c];
}

__global__ void __launch_bounds__(256) k_wsq_final(const float* __restrict__ part,
                                                   float* __restrict__ wsq) {
  const int col = blockIdx.x * 256 + threadIdx.x;
  float s = 0.f;
  #pragma unroll
  for (int kb = 0; kb < 16; ++kb) s += part[(size_t)kb * OUTF + col];
  wsq[col] = s;
}

// ---- fused GEMM: out = xsq[row] + wsq[col] - 2 * (x @ w) ----
// 256x256 tile, BK=64, 16 waves (4Mx4N, 64x64 out each), 1024 threads,
// __launch_bounds__(1024,4) -> <=128 VGPR -> 4 waves/SIMD (TLP stall-fill).
// Double-buffered 128 KiB LDS; 2-barrier/tile counted-vmcnt pipeline
// (2 K-tiles in flight, vmcnt(4) steady, never 0 mid-loop); T2 swizzle; T5 setprio.
// XCD remap: each XCD owns an 8-panel A-strip (4 MB, fits its private L2).
// LDS per buffer (65536 B): A [256][64] bf16 at +0, B [256][64] at +32768.
// Swizzle: element (r, c-byte) at LDS byte r*128 + (c ^ ((r&7)<<4)), both-sides.
__global__ void __launch_bounds__(1024, 4) k_gemm(const u16* __restrict__ A,
                                                  const u16* __restrict__ Bt,
                                                  const float* __restrict__ xsq,
                                                  const float* __restrict__ wsq,
                                                  float* __restrict__ out) {
  extern __shared__ __attribute__((aligned(16))) char lds_raw[];

  const int tid = threadIdx.x;
  const int wave = tid >> 6, lane = tid & 63;
  // XCD-aware remap: xcd = bid&7 (dispatch round-robin), loc = bid>>3.
  // by = xcd*8 + (loc&7): per-XCD contiguous 2048-row A-strip (4 MB bf16, L2-fit).
  const int xcd = blockIdx.x & 7;
  const int loc = blockIdx.x >> 3;
  const int by = (xcd << 3) | (loc & 7);   // 0..63
  const int bx = loc >> 3;                 // 0..7
  const int rowBase = by * BM;
  const int colBase = bx * BN;
  const int wr = wave >> 2, wc = wave & 3; // 4 (M) x 4 (N) waves

  // staging addresses (linear LDS dest, pre-swizzled global source)
  const int srow  = tid >> 3;                                          // 0..127
  const int ke    = (((tid & 7) * 16) ^ (((tid >> 3) & 7) << 4)) >> 1; // elem col
  const u16* aS = A  + (size_t)(rowBase + srow) * INF + ke;
  const u16* bS = Bt + (size_t)(colBase + srow) * INF + ke;
  char* ldsw = lds_raw + tid * 16;

  // 4 issues/thread/tile: A rows [0,128)+[128,256), B rows [0,128)+[128,256)
  auto STAGE = [&](int parity, int t) {
    const int kk = t * BK;
    char* dst = ldsw + parity * 65536;
    load_lds16(aS + (size_t)0 * INF + kk,       dst);
    load_lds16(aS + (size_t)128 * INF + kk,     dst + 16384);
    load_lds16(bS + (size_t)0 * INF + kk,       dst + 32768);
    load_lds16(bS + (size_t)128 * INF + kk,     dst + 49152);
  };

  // fragment read addressing (swizzled)
  const int rf  = lane & 15;
  const int hi  = lane >> 4;                 // 0..3 (k-slice)
  const int swz = (rf & 7) << 4;
  const int aRd = (wr * 64 + rf) * 128;             // + m*2048 + ((ks*64+hi*16)^swz)
  const int bRd = 32768 + (wc * 64 + rf) * 128;     // + n*2048 + ((ks*64+hi*16)^swz)

  f32x4 acc[4][4] = {};

  // prologue: 2 K-tiles in flight (8 loads/thread outstanding)
  STAGE(0, 0);
  STAGE(1, 1);

  #pragma unroll
  for (int t = 0; t < NT; ++t) {
    if (t < NT - 1) asm volatile("s_waitcnt vmcnt(4)" ::: "memory");
    else            asm volatile("s_waitcnt vmcnt(0)" ::: "memory");
    __builtin_amdgcn_s_barrier();            // buf[t&1] resident for all waves

    const char* buf = lds_raw + (t & 1) * 65536;

    #pragma unroll
    for (int ks = 0; ks < 2; ++ks) {
      const int ko = (ks * 64 + hi * 16) ^ swz;
      bf16x8 b[4];
      #pragma unroll
      for (int nn = 0; nn < 4; ++nn)
        b[nn] = *reinterpret_cast<const bf16x8*>(buf + bRd + nn * 2048 + ko);
      __builtin_amdgcn_s_setprio(1);
      #pragma unroll
      for (int mm = 0; mm < 4; ++mm) {
        bf16x8 a = *reinterpret_cast<const bf16x8*>(buf + aRd + mm * 2048 + ko);
        #pragma unroll
        for (int nn = 0; nn < 4; ++nn)
          acc[mm][nn] = __builtin_amdgcn_mfma_f32_16x16x32_bf16(
              a, b[nn], acc[mm][nn], 0, 0, 0);
      }
      __builtin_amdgcn_s_setprio(0);
    }

    asm volatile("s_waitcnt lgkmcnt(0)" ::: "memory");  // my reads of buf[t&1] landed
    __builtin_amdgcn_s_barrier();                        // all waves done reading
    if (t + 2 < NT) STAGE(t & 1, t + 2);                 // overwrite freed buffer
  }

  // ---- epilogue: C/D layout col = lane&15, row = (lane>>4)*4 + j ----
  const int cj = lane & 15;
  const int rg = hi * 4;
  #pragma unroll
  for (int m = 0; m < 4; ++m) {
    #pragma unroll
    for (int j = 0; j < 4; ++j) {
      const int row = rowBase + wr * 64 + m * 16 + rg + j;
      const float xs = xsq[row];
      #pragma unroll
      for (int n = 0; n < 4; ++n) {
        const int col = colBase + wc * 64 + n * 16 + cj;
        out[(size_t)row * OUTF + col] = xs + wsq[col] - 2.0f * acc[m][n][j];
      }
    }
  }
}

extern "C" void kernel_launch(void* const* d_in, const int* in_sizes, int n_in,
                              void* d_out, int out_size, void* d_ws, size_t ws_size,
                              hipStream_t stream) {
  const float* x = (const float*)d_in[0];
  const float* w = (const float*)d_in[1];
  float* out = (float*)d_out;

  char* ws = (char*)d_ws;
  u16* xb    = (u16*)(ws);                    // 16384*1024*2 = 33554432 B
  u16* wt    = (u16*)(ws + 33554432);         // 2048*1024*2  =  4194304 B
  float* xsq = (float*)(ws + 37748736);       // 16384*4      =    65536 B
  float* wsq = (float*)(ws + 37814272);       // 2048*4       =     8192 B
  float* prt = (float*)(ws + 37822464);       // 16*2048*4    =   131072 B

  (void)hipFuncSetAttribute(reinterpret_cast<const void*>(k_gemm),
                            hipFuncAttributeMaxDynamicSharedMemorySize, 131072);

  k_convert_x<<<BATCH, 256, 0, stream>>>(x, xb, xsq);
  k_convert_w<<<dim3(OUTF / 64, INF / 64), 256, 0, stream>>>(w, wt, prt);
  k_wsq_final<<<OUTF / 256, 256, 0, stream>>>(prt, wsq);
  k_gemm<<<512, 1024, 131072, stream>>>(xb, wt, xsq, wsq, out);
}